// Round 1
// baseline (216.782 us; speedup 1.0000x reference)
//
#include <hip/hip_runtime.h>

// Problem constants (from reference setup_inputs)
constexpr int B  = 32;
constexpr int C  = 3;
constexpr int H  = 512;
constexpr int W  = 512;
constexpr int HP = H / 4;    // 128 pooled rows
constexpr int WP = W / 4;    // 128 pooled cols
constexpr int NP = B * HP * WP;   // 524288 pooled pixels

// Tile: 32 (x) x 16 (y) owned pooled pixels, halo 1 row ABOVE + 1 col LEFT.
// Pair-counting: E*NP = 2*sum(adjacent-pair diffs^2) + sum(border p^2);
// each block counts pairs (up-neighbor, left-neighbor) for its OWNED pixels
// only -> halo needed only on top/left. Zero-filled halo at image borders
// makes the border term (c-0)^2 = c^2 with weight 1 automatically.
//
// v2 vs v1 (64x32 tiles, 256 blocks): v1 was latency-bound — 1 block/CU
// (Occupancy 10%), VGPR=20 (compiler issued ~2 loads at a time), effective
// read BW 2.45 TB/s. Halo redundancy is L3-absorbed (FETCH_SIZE ~107MB vs
// 207MB logical), so smaller tiles cost ~nothing on HBM:
//   32x16 tiles -> 1024 blocks = 4 blocks/CU = 16 waves/CU, and Phase A
//   batches 8 float4 loads per channel into registers for ILP.
constexpr int TX = 32;            // owned cols per tile
constexpr int TY = 16;            // owned rows per tile
constexpr int HX = TX + 1;        // 33 (left halo)
constexpr int HY = TY + 1;        // 17 (top halo)
constexpr int TILES_X = WP / TX;  // 4
constexpr int TILES_Y = HP / TY;  // 8
constexpr int NBLOCKS = B * TILES_X * TILES_Y;  // 1024

__global__ __launch_bounds__(256, 4) void spatial_loss_fused(
        const float* __restrict__ x,
        const float* __restrict__ pred,
        float* __restrict__ out) {
    __shared__ float pt[HY][HX];   // 17x33 floats = 2.2 KB; flat addr == i

    int blk = blockIdx.x;
    int b   = blk >> 5;           // image (32 tiles per image)
    int ty  = (blk >> 2) & 7;     // tile row (0..7)
    int tx  = blk & 3;            // tile col (0..3)
    int y0  = ty * TY;
    int x0  = tx * TX;
    int tid = threadIdx.x;

    // ---- Phase A: pooled channel-mean diff for the 17x33 halo tile ----
    // 561 entries / 256 threads = 3 strided iterations (last partial).
    for (int i = tid; i < HY * HX; i += 256) {
        int hy = i / HX;
        int hx = i - hy * HX;
        int gy = y0 + hy - 1;     // pooled coords, -1..127
        int gx = x0 + hx - 1;
        float s = 0.0f;
        if ((unsigned)gy < (unsigned)HP && (unsigned)gx < (unsigned)WP) {
            size_t base = (((size_t)b * C) * H + (size_t)gy * 4) * W + (size_t)gx * 4;
            const float4* xb = (const float4*)(x    + base);
            const float4* pb = (const float4*)(pred + base);
            constexpr size_t CS = (size_t)H * W / 4;   // channel stride in float4
            constexpr size_t RS = W / 4;               // row stride in float4
            float s0 = 0.0f, s1 = 0.0f;
            #pragma unroll
            for (int c = 0; c < C; ++c) {
                // Batch all 8 loads of this channel into registers BEFORE any
                // arithmetic -> 8 float4 loads in flight per wave (v1's codegen
                // at VGPR=20 had ~2, serializing on vmcnt).
                float4 xr0 = xb[c * CS + 0 * RS];
                float4 xr1 = xb[c * CS + 1 * RS];
                float4 xr2 = xb[c * CS + 2 * RS];
                float4 xr3 = xb[c * CS + 3 * RS];
                float4 pr0 = pb[c * CS + 0 * RS];
                float4 pr1 = pb[c * CS + 1 * RS];
                float4 pr2 = pb[c * CS + 2 * RS];
                float4 pr3 = pb[c * CS + 3 * RS];
                s0 += (xr0.x - pr0.x) + (xr0.y - pr0.y) + (xr0.z - pr0.z) + (xr0.w - pr0.w);
                s1 += (xr1.x - pr1.x) + (xr1.y - pr1.y) + (xr1.z - pr1.z) + (xr1.w - pr1.w);
                s0 += (xr2.x - pr2.x) + (xr2.y - pr2.y) + (xr2.z - pr2.z) + (xr2.w - pr2.w);
                s1 += (xr3.x - pr3.x) + (xr3.y - pr3.y) + (xr3.z - pr3.z) + (xr3.w - pr3.w);
            }
            s = (s0 + s1) * (1.0f / 48.0f);
        }
        pt[hy][hx] = s;   // addr = i -> consecutive lanes, conflict-free
    }
    __syncthreads();

    // ---- Phase B: pair-counted gradient sum over owned 16x32 pixels ----
    float acc = 0.0f;
    #pragma unroll
    for (int j = 0; j < (TY * TX) / 256; ++j) {
        int i  = tid + j * 256;
        int r  = i >> 5;          // 0..15
        int xx = i & 31;          // 0..31
        int gy = y0 + r;
        int gx = x0 + xx;
        float c  = pt[r + 1][xx + 1];
        float up = pt[r + 0][xx + 1];   // zero if gy==0 (image border)
        float lf = pt[r + 1][xx + 0];   // zero if gx==0
        float dy = c - up;
        float dx = c - lf;
        float wy = (gy > 0) ? 2.0f : 1.0f;  // interior pair counted twice
        float wx = (gx > 0) ? 2.0f : 1.0f;
        acc += wy * dy * dy + wx * dx * dx;
        if (gy == HP - 1) acc += c * c;     // bottom border (d3)
        if (gx == WP - 1) acc += c * c;     // right border (d1)
    }

    // wave64 shuffle reduce -> LDS -> one pre-scaled atomicAdd per block
    #pragma unroll
    for (int off = 32; off > 0; off >>= 1)
        acc += __shfl_down(acc, off, 64);

    __shared__ float ws_red[4];
    int lane = tid & 63;
    int wid  = tid >> 6;
    if (lane == 0) ws_red[wid] = acc;
    __syncthreads();
    if (tid == 0) {
        float s = ws_red[0] + ws_red[1] + ws_red[2] + ws_red[3];
        atomicAdd(out, s * (1.0f / (float)NP));
    }
}

extern "C" void kernel_launch(void* const* d_in, const int* in_sizes, int n_in,
                              void* d_out, int out_size, void* d_ws, size_t ws_size,
                              hipStream_t stream) {
    const float* x    = (const float*)d_in[0];
    const float* pred = (const float*)d_in[1];
    float* out = (float*)d_out;

    // d_out is poisoned 0xAA before every launch — zero it (capture-safe).
    hipMemsetAsync(out, 0, sizeof(float), stream);

    spatial_loss_fused<<<NBLOCKS, 256, 0, stream>>>(x, pred, out);
}